// Round 17
// baseline (217.604 us; speedup 1.0000x reference)
//
#include <hip/hip_runtime.h>
#include <hip/hip_bf16.h>
#include <stdint.h>

typedef __bf16 bf16;
typedef __bf16 bf16x8 __attribute__((ext_vector_type(8)));
typedef __bf16 bf16x4 __attribute__((ext_vector_type(4)));
typedef float f32x4 __attribute__((ext_vector_type(4)));
typedef unsigned u32x2 __attribute__((ext_vector_type(2)));

#define F_DIM 1024
#define NSEQ  2048
#define NB    4
#define NH    16
#define HD    64
#define MROWS (NB * NSEQ)  /* 8192 */
#define LOG2E 1.44269504088896340736f

__device__ __forceinline__ void gload_lds16(const void* g, void* l) {
    __builtin_amdgcn_global_load_lds(
        (__attribute__((address_space(1))) void*)g,
        (__attribute__((address_space(3))) void*)l,
        16, 0, 0);
}

__device__ __forceinline__ unsigned lds_addr(const void* p) {
    return (unsigned)(size_t)(__attribute__((address_space(3))) const void*)p;
}

__device__ __forceinline__ float exp2_fast(float x) {
    float r;
    asm("v_exp_f32 %0, %1" : "=v"(r) : "v"(x));
    return r;
}

__device__ __forceinline__ unsigned cvtpk_bf16(float lo, float hi) {
    unsigned r;
    asm("v_cvt_pk_bf16_f32 %0, %1, %2" : "=v"(r) : "v"(lo), "v"(hi));
    return r;
}

// ---------------------------------------------------------------------------
// Fused prep: blocks [0,8192) = double layernorm row; [8192,12288) = weight
// convert (dsts contiguous wqb|wkvb|wob).
// ---------------------------------------------------------------------------
__global__ __launch_bounds__(256) void prep_kernel(
    const float* __restrict__ x,
    const float* __restrict__ g1, const float* __restrict__ b1,
    const float* __restrict__ g2, const float* __restrict__ b2,
    bf16* __restrict__ xn, bf16* __restrict__ cn,
    const float* __restrict__ wq, const float* __restrict__ wkv,
    const float* __restrict__ wo, bf16* __restrict__ wdst)
{
    const int t = threadIdx.x;
    if (blockIdx.x >= MROWS) {
        const int i = (blockIdx.x - MROWS) * 256 + t;   // float4 units
        const float* src;
        int si;
        if (i < 262144)       { src = wq;  si = i; }
        else if (i < 786432)  { src = wkv; si = i - 262144; }
        else                  { src = wo;  si = i - 786432; }
        float4 v = reinterpret_cast<const float4*>(src)[si];
        bf16x4 o = { (bf16)v.x, (bf16)v.y, (bf16)v.z, (bf16)v.w };
        reinterpret_cast<bf16x4*>(wdst)[i] = o;
        return;
    }
    const int row = blockIdx.x;
    float4 v = reinterpret_cast<const float4*>(x + (size_t)row * F_DIM)[t];
    float s  = v.x + v.y + v.z + v.w;
    float ss = v.x * v.x + v.y * v.y + v.z * v.z + v.w * v.w;
#pragma unroll
    for (int m = 1; m < 64; m <<= 1) {
        s  += __shfl_xor(s, m);
        ss += __shfl_xor(ss, m);
    }
    __shared__ float red[8];
    const int w = t >> 6;
    if ((t & 63) == 0) { red[w] = s; red[4 + w] = ss; }
    __syncthreads();
    s  = red[0] + red[1] + red[2] + red[3];
    ss = red[4] + red[5] + red[6] + red[7];
    const float mu  = s * (1.0f / F_DIM);
    const float var = fmaxf(ss * (1.0f / F_DIM) - mu * mu, 0.0f);
    const float rs  = rsqrtf(var + 1e-5f);

    float4 G1 = reinterpret_cast<const float4*>(g1)[t];
    float4 B1 = reinterpret_cast<const float4*>(b1)[t];
    float4 G2 = reinterpret_cast<const float4*>(g2)[t];
    float4 B2 = reinterpret_cast<const float4*>(b2)[t];
    const float h0 = (v.x - mu) * rs, h1 = (v.y - mu) * rs;
    const float h2 = (v.z - mu) * rs, h3 = (v.w - mu) * rs;
    bf16x4 o1 = { (bf16)(h0 * G1.x + B1.x), (bf16)(h1 * G1.y + B1.y),
                  (bf16)(h2 * G1.z + B1.z), (bf16)(h3 * G1.w + B1.w) };
    bf16x4 o2 = { (bf16)(h0 * G2.x + B2.x), (bf16)(h1 * G2.y + B2.y),
                  (bf16)(h2 * G2.z + B2.z), (bf16)(h3 * G2.w + B2.w) };
    *reinterpret_cast<bf16x4*>(xn + (size_t)row * F_DIM + t * 4) = o1;
    *reinterpret_cast<bf16x4*>(cn + (size_t)row * F_DIM + t * 4) = o2;
}

// ---------------------------------------------------------------------------
// Merged Q/KV projection GEMM, K=1024, BK=32. 1536 blocks, XCD-chunked.
// ---------------------------------------------------------------------------
__global__ __launch_bounds__(256, 2) void qkv_gemm(
    const bf16* __restrict__ xn, const bf16* __restrict__ cn,
    const bf16* __restrict__ wq, const bf16* __restrict__ wkv,
    bf16* __restrict__ qb, bf16* __restrict__ kvb, float qscale)
{
    __shared__ bf16 As[128 * 32];
    __shared__ bf16 Bs[128 * 32];
    const int t = threadIdx.x;
    const int lane = t & 63;
    const int w = t >> 6;
    const int wr = w >> 1, wc = w & 1;

    int flat = blockIdx.x;
    flat = (flat & 7) * 192 + (flat >> 3);          // XCD chunk (1536/8 = 192)

    const bf16 *A, *B;
    bf16* C;
    int N, bm, bn;
    float osc;
    if (flat < 512) {
        A = xn; B = wq; C = qb; N = 1024; osc = qscale;
        bm = (flat >> 3) * 128; bn = (flat & 7) * 128;
    } else {
        const int f = flat - 512;
        A = cn; B = wkv; C = kvb; N = 2048; osc = 1.0f;
        bm = (f >> 4) * 128; bn = (f & 15) * 128;
    }

    const int r = lane & 15;
    const int kg = (lane >> 4) * 8;

    f32x4 acc[4][4];
#pragma unroll
    for (int i = 0; i < 4; i++)
#pragma unroll
        for (int j = 0; j < 4; j++) acc[i][j] = (f32x4){0.f, 0.f, 0.f, 0.f};

    const int c0 = t, c1 = 256 + t;
    const size_t aoff0 = (size_t)(bm + (c0 >> 2)) * F_DIM + (c0 & 3) * 8;
    const size_t aoff1 = (size_t)(bm + (c1 >> 2)) * F_DIM + (c1 & 3) * 8;
    const size_t boff0 = (size_t)(bn + (c0 >> 2)) * F_DIM + (c0 & 3) * 8;
    const size_t boff1 = (size_t)(bn + (c1 >> 2)) * F_DIM + (c1 & 3) * 8;
    bf16* lA0 = As + (size_t)(0 * 256 + w * 64) * 8;
    bf16* lA1 = As + (size_t)(1 * 256 + w * 64) * 8;
    bf16* lB0 = Bs + (size_t)(0 * 256 + w * 64) * 8;
    bf16* lB1 = Bs + (size_t)(1 * 256 + w * 64) * 8;

    for (int kt = 0; kt < F_DIM; kt += 32) {
        gload_lds16(A + aoff0 + kt, lA0);
        gload_lds16(A + aoff1 + kt, lA1);
        gload_lds16(B + boff0 + kt, lB0);
        gload_lds16(B + boff1 + kt, lB1);
        __syncthreads();
        bf16x8 af[4], bfr[4];
#pragma unroll
        for (int mi = 0; mi < 4; mi++)
            af[mi] = *(const bf16x8*)(As + (wr * 64 + mi * 16 + r) * 32 + kg);
#pragma unroll
        for (int ni = 0; ni < 4; ni++)
            bfr[ni] = *(const bf16x8*)(Bs + (wc * 64 + ni * 16 + r) * 32 + kg);
#pragma unroll
        for (int mi = 0; mi < 4; mi++)
#pragma unroll
            for (int ni = 0; ni < 4; ni++)
                acc[mi][ni] = __builtin_amdgcn_mfma_f32_16x16x32_bf16(
                    af[mi], bfr[ni], acc[mi][ni], 0, 0, 0);
        __syncthreads();
    }

    const int g = lane >> 4;
#pragma unroll
    for (int mi = 0; mi < 4; mi++) {
#pragma unroll
        for (int ni = 0; ni < 4; ni++) {
            const int col = bn + wc * 64 + ni * 16 + r;
#pragma unroll
            for (int j = 0; j < 4; j++) {
                const int row = bm + wr * 64 + mi * 16 + g * 4 + j;
                C[(size_t)row * N + col] = (bf16)(acc[mi][ni][j] * osc);
            }
        }
    }
}

// ---------------------------------------------------------------------------
// Output GEMM: out = ao * Wo^T + x (fp32). BK=32. 512 blocks, XCD-chunked.
// ---------------------------------------------------------------------------
__global__ __launch_bounds__(256, 2) void o_gemm(
    const bf16* __restrict__ A, const bf16* __restrict__ B,
    float* __restrict__ Cf, const float* __restrict__ skip)
{
    __shared__ bf16 As[128 * 32];
    __shared__ bf16 Bs[128 * 32];
    const int t = threadIdx.x;
    const int lane = t & 63;
    const int w = t >> 6;
    const int wr = w >> 1, wc = w & 1;

    int flat = blockIdx.x;                          // 512 blocks: 64 M x 8 N
    flat = (flat & 7) * 64 + (flat >> 3);           // XCD chunk
    const int bm = (flat >> 3) * 128;
    const int bn = (flat & 7) * 128;

    const int r = lane & 15;
    const int kg = (lane >> 4) * 8;

    f32x4 acc[4][4];
#pragma unroll
    for (int i = 0; i < 4; i++)
#pragma unroll
        for (int j = 0; j < 4; j++) acc[i][j] = (f32x4){0.f, 0.f, 0.f, 0.f};

    const int c0 = t, c1 = 256 + t;
    const size_t aoff0 = (size_t)(bm + (c0 >> 2)) * F_DIM + (c0 & 3) * 8;
    const size_t aoff1 = (size_t)(bm + (c1 >> 2)) * F_DIM + (c1 & 3) * 8;
    const size_t boff0 = (size_t)(bn + (c0 >> 2)) * F_DIM + (c0 & 3) * 8;
    const size_t boff1 = (size_t)(bn + (c1 >> 2)) * F_DIM + (c1 & 3) * 8;
    bf16* lA0 = As + (size_t)(0 * 256 + w * 64) * 8;
    bf16* lA1 = As + (size_t)(1 * 256 + w * 64) * 8;
    bf16* lB0 = Bs + (size_t)(0 * 256 + w * 64) * 8;
    bf16* lB1 = Bs + (size_t)(1 * 256 + w * 64) * 8;

    for (int kt = 0; kt < F_DIM; kt += 32) {
        gload_lds16(A + aoff0 + kt, lA0);
        gload_lds16(A + aoff1 + kt, lA1);
        gload_lds16(B + boff0 + kt, lB0);
        gload_lds16(B + boff1 + kt, lB1);
        __syncthreads();
        bf16x8 af[4], bfr[4];
#pragma unroll
        for (int mi = 0; mi < 4; mi++)
            af[mi] = *(const bf16x8*)(As + (wr * 64 + mi * 16 + r) * 32 + kg);
#pragma unroll
        for (int ni = 0; ni < 4; ni++)
            bfr[ni] = *(const bf16x8*)(Bs + (wc * 64 + ni * 16 + r) * 32 + kg);
#pragma unroll
        for (int mi = 0; mi < 4; mi++)
#pragma unroll
            for (int ni = 0; ni < 4; ni++)
                acc[mi][ni] = __builtin_amdgcn_mfma_f32_16x16x32_bf16(
                    af[mi], bfr[ni], acc[mi][ni], 0, 0, 0);
        __syncthreads();
    }

    const int g = lane >> 4;
#pragma unroll
    for (int mi = 0; mi < 4; mi++) {
#pragma unroll
        for (int ni = 0; ni < 4; ni++) {
            const int col = bn + wc * 64 + ni * 16 + r;
#pragma unroll
            for (int j = 0; j < 4; j++) {
                const int row = bm + wr * 64 + mi * 16 + g * 4 + j;
                Cf[(size_t)row * F_DIM + col] =
                    acc[mi][ni][j] + skip[(size_t)row * F_DIM + col];
            }
        }
    }
}

// ---------------------------------------------------------------------------
// Flash attention v16: KVBLK=64 DOUBLE-BUFFERED, compile-time buffer indices
// (manual 2-body unroll — fixes v4's runtime-index + LDS-growth failures:
// LDS 50.4KB ~= round-14's 51.2KB, occupancy unchanged). Per tile:
// vmcnt(0) [loads issued a full compute-phase ago -> near-free] -> barrier ->
// issue next tile's 2 gloads into other buffer -> compute. 8 waves, QBLK=128.
// v8 tile body + v10 early P-pack (s4[4]: LOWER reg pressure than round-14).
// ---------------------------------------------------------------------------
__global__ __launch_bounds__(512)
__attribute__((amdgpu_waves_per_eu(4, 5)))
void attn_kernel(
    const bf16* __restrict__ q, const bf16* __restrict__ kvp,
    bf16* __restrict__ o)
{
    __shared__ __align__(16) bf16 Ks0[64 * 64];     // [kv][64d], chunk-XOR-swz
    __shared__ __align__(16) bf16 Ks1[64 * 64];
    __shared__ __align__(16) bf16 Vs0[64 * 64];     // [kvb=16][dblk=4][4kv][16d]
    __shared__ __align__(16) bf16 Vs1[64 * 64];
    __shared__ __align__(16) bf16 Ps[8][16 * 72];   // per-wave P [q][64kv]

    const int bid = blockIdx.x;
    const int idx = (bid & 7) * 128 + (bid >> 3);   // XCD-chunked (1024 % 8 == 0)
    const int bh = idx >> 4;
    const int qt = idx & 15;
    const int b = bh >> 4, h = bh & 15;

    const int t = threadIdx.x, lane = t & 63, w = t >> 6;
    const int r = lane & 15, g = lane >> 4;

    const size_t rowq = (size_t)b * NSEQ;

    // --- staging source offsets (1 K-chunk + 1 V-chunk per thread) ---
    const int p = t;                                // dest 16B-chunk 0..511
    const int krow = p >> 3;                        // 0..63
    const int kcol = (p & 7) ^ (krow & 7);
    const size_t ksrc = (size_t)(rowq + krow) * (2 * F_DIM) + h * HD + kcol * 8;
    const int kvb = p >> 5, dblk = (p >> 3) & 3;
    const int kvl = (p & 7) >> 1, d8 = p & 1;
    const size_t vsrc = (size_t)(rowq + kvb * 4 + kvl) * (2 * F_DIM) + F_DIM + h * HD
                        + dblk * 16 + d8 * 8;
    const unsigned wch = (unsigned)(t & ~63) * 8;   // wave-uniform dest offset
    bf16* kd0 = Ks0 + wch;  bf16* kd1 = Ks1 + wch;
    bf16* vd0 = Vs0 + wch;  bf16* vd1 = Vs1 + wch;

    // --- Q fragments (B-operand: lane holds Q[q=r][d = kk*32 + g*8 ..]) ---
    const int q0 = qt * 128 + w * 16;
    bf16x8 qf[2];
#pragma unroll
    for (int kk = 0; kk < 2; kk++)
        qf[kk] = *(const bf16x8*)(q + (rowq + q0 + r) * F_DIM + h * HD + kk * 32 + g * 8);

    f32x4 oacc[4];
#pragma unroll
    for (int i = 0; i < 4; i++) oacc[i] = (f32x4){0.f, 0.f, 0.f, 0.f};
    float m_r = -1e30f, l_r = 0.f;

    const unsigned va0   = lds_addr(Vs0) + (unsigned)(g * 1024 + r * 8);
    const unsigned va1   = lds_addr(Vs1) + (unsigned)(g * 1024 + r * 8);
    const unsigned pbase = lds_addr(&Ps[w][0]) + (unsigned)((r * 72 + g * 8) * 2);

    // --- prologue: stage tile 0 into buffer 0 ---
    gload_lds16(kvp + ksrc, kd0);
    gload_lds16(kvp + vsrc, vd0);

    // tile body macro: compute from KSB/VAB, prefetch tile at NOFF into NKD/NVD
#define ATTN_TILE(KSB, VAB, NKD, NVD, NOFF, MORE)                              \
    {                                                                          \
        asm volatile("s_waitcnt vmcnt(0)" ::: "memory");                       \
        __builtin_amdgcn_s_barrier();                                          \
        if (MORE) {                                                            \
            gload_lds16(kvp + ksrc + (NOFF), NKD);                             \
            gload_lds16(kvp + vsrc + (NOFF), NVD);                             \
        }                                                                      \
        f32x4 s4[4];                                                           \
        _Pragma("unroll")                                                      \
        for (int nt = 0; nt < 4; nt++) s4[nt] = (f32x4){0.f, 0.f, 0.f, 0.f};   \
        __builtin_amdgcn_s_setprio(1);                                         \
        _Pragma("unroll")                                                      \
        for (int kk = 0; kk < 2; kk++) {                                       \
            _Pragma("unroll")                                                  \
            for (int nt = 0; nt < 4; nt++) {                                   \
                const unsigned lb = (unsigned)((nt * 16 + r) * 128 + kk * 64   \
                                    + g * 16) ^ (unsigned)((r & 7) << 4);      \
                bf16x8 kf = *(const bf16x8*)((const char*)(KSB) + lb);         \
                s4[nt] = __builtin_amdgcn_mfma_f32_16x16x32_bf16(              \
                    kf, qf[kk], s4[nt], 0, 0, 0);                              \
            }                                                                  \
        }                                                                      \
        __builtin_amdgcn_s_setprio(0);                                         \
        float mx = s4[0][0];                                                   \
        _Pragma("unroll")                                                      \
        for (int nt = 0; nt < 4; nt++)                                         \
            _Pragma("unroll")                                                  \
            for (int j = 0; j < 4; j++) mx = fmaxf(mx, s4[nt][j]);             \
        mx = fmaxf(mx, __shfl_xor(mx, 16));                                    \
        mx = fmaxf(mx, __shfl_xor(mx, 32));                                    \
        if (!__all(mx <= m_r + 8.0f)) {                                        \
            const float mnew = fmaxf(m_r, mx);                                 \
            const float alpha = exp2_fast(m_r - mnew);                         \
            l_r *= alpha;                                                      \
            _Pragma("unroll")                                                  \
            for (int j = 0; j < 4; j++) {                                      \
                const float aj = __shfl(alpha, g * 4 + j);                     \
                _Pragma("unroll")                                              \
                for (int ntd = 0; ntd < 4; ntd++) oacc[ntd][j] *= aj;          \
            }                                                                  \
            m_r = mnew;                                                        \
        }                                                                      \
        u32x2 pa2[4];                                                          \
        float ps = 0.f;                                                        \
        _Pragma("unroll")                                                      \
        for (int nt = 0; nt < 4; nt++) {                                       \
            const float e0 = exp2_fast(s4[nt][0] - m_r);                       \
            const float e1 = exp2_fast(s4[nt][1] - m_r);                       \
            const float e2 = exp2_fast(s4[nt][2] - m_r);                       \
            const float e3 = exp2_fast(s4[nt][3] - m_r);                       \
            ps += (e0 + e1) + (e2 + e3);                                       \
            pa2[nt] = (u32x2){ cvtpk_bf16(e0, e1), cvtpk_bf16(e2, e3) };       \
        }                                                                      \
        ps += __shfl_xor(ps, 16);                                              \
        ps += __shfl_xor(ps, 32);                                              \
        l_r += ps;                                                             \
        _Pragma("unroll")                                                      \
        for (int nt = 0; nt < 4; nt++)                                         \
            *(u32x2*)&Ps[w][r * 72 + nt * 16 + g * 4] = pa2[nt];               \
        asm volatile("s_waitcnt lgkmcnt(0)" ::: "memory");                     \
        bf16x8 pf[2];                                                          \
        u32x2 vt[2][4][2];                                                     \
        _Pragma("unroll")                                                      \
        for (int kk2 = 0; kk2 < 2; kk2++) {                                    \
            const unsigned pa = pbase + (unsigned)(kk2 * 64);                  \
            asm volatile("ds_read_b128 %0, %1" : "=v"(pf[kk2]) : "v"(pa));     \
            _Pragma("unroll")                                                  \
            for (int ntd = 0; ntd < 4; ntd++) {                                \
                const unsigned a = (VAB) + (unsigned)(kk2 * 4096 + ntd * 128); \
                asm volatile("ds_read_b64_tr_b16 %0, %2\n\t"                   \
                             "ds_read_b64_tr_b16 %1, %2 offset:512"            \
                             : "=&v"(vt[kk2][ntd][0]), "=&v"(vt[kk2][ntd][1])  \
                             : "v"(a));                                        \
            }                                                                  \
        }                                                                      \
        asm volatile("s_waitcnt lgkmcnt(0)" ::: "memory");                     \
        __builtin_amdgcn_sched_barrier(0);                                     \
        __builtin_amdgcn_s_setprio(1);                                         \
        _Pragma("unroll")                                                      \
        for (int kk2 = 0; kk2 < 2; kk2++)                                      \
            _Pragma("unroll")                                                  \
            for (int ntd = 0; ntd < 4; ntd++) {                                \
                union { u32x2 hl[2]; bf16x8 v; } u;                            \
                u.hl[0] = vt[kk2][ntd][0];                                     \
                u.hl[1] = vt[kk2][ntd][1];                                     \
                oacc[ntd] = __builtin_amdgcn_mfma_f32_16x16x32_bf16(           \
                    pf[kk2], u.v, oacc[ntd], 0, 0, 0);                         \
            }                                                                  \
        __builtin_amdgcn_s_setprio(0);                                         \
    }

    for (int kv0 = 0; kv0 < NSEQ; kv0 += 128) {
        const size_t offB = (size_t)(kv0 + 64) * (2 * F_DIM);    // tile -> buf1
        const size_t offA = (size_t)(kv0 + 128) * (2 * F_DIM);   // tile -> buf0
        const bool moreA = (kv0 + 128 < NSEQ);
        // tile kv0 from buf0; prefetch kv0+64 into buf1 (always valid)
        ATTN_TILE(Ks0, va0, kd1, vd1, offB, true);
        // tile kv0+64 from buf1; prefetch kv0+128 into buf0 (guarded)
        ATTN_TILE(Ks1, va1, kd0, vd0, offA, moreA);
    }
#undef ATTN_TILE

    // --- epilogue: normalize + store ---
    float rl[4];
#pragma unroll
    for (int j = 0; j < 4; j++) {
        const float lj = __shfl(l_r, g * 4 + j);
        rl[j] = 1.0f / lj;
    }
#pragma unroll
    for (int ntd = 0; ntd < 4; ntd++)
#pragma unroll
        for (int j = 0; j < 4; j++) {
            const int row = q0 + g * 4 + j;
            o[(rowq + row) * F_DIM + h * HD + ntd * 16 + r] =
                (bf16)(oacc[ntd][j] * rl[j]);
        }
}

// ---------------------------------------------------------------------------
extern "C" void kernel_launch(void* const* d_in, const int* in_sizes, int n_in,
                              void* d_out, int out_size, void* d_ws, size_t ws_size,
                              hipStream_t stream)
{
    const float* x     = (const float*)d_in[0];
    const float* Wq    = (const float*)d_in[1];
    const float* Wkv   = (const float*)d_in[2];
    const float* Wo    = (const float*)d_in[3];
    const float* ln_g  = (const float*)d_in[4];
    const float* ln_b  = (const float*)d_in[5];
    const float* lnc_g = (const float*)d_in[6];
    const float* lnc_b = (const float*)d_in[7];
    float* out = (float*)d_out;

    bf16* xn   = (bf16*)d_ws;
    bf16* cn   = xn  + (size_t)MROWS * F_DIM;
    bf16* qb   = cn  + (size_t)MROWS * F_DIM;
    bf16* kvb  = qb  + (size_t)MROWS * F_DIM;
    bf16* wqb  = kvb + (size_t)MROWS * 2 * F_DIM;   // wqb|wkvb|wob contiguous
    bf16* wkvb = wqb + (size_t)F_DIM * F_DIM;
    bf16* wob  = wkvb + (size_t)2 * F_DIM * F_DIM;
    bf16* ao   = xn;  // xn dead after qkv-GEMM

    // layernorms + weight converts fused into one launch
    prep_kernel<<<dim3(MROWS + 4096), dim3(256), 0, stream>>>(
        x, ln_g, ln_b, lnc_g, lnc_b, xn, cn, Wq, Wkv, Wo, wqb);

    // q = (xn * Wq^T) * 0.125 * log2(e) ; kv = cn * Wkv^T   (one launch)
    qkv_gemm<<<dim3(1536), dim3(256), 0, stream>>>(
        xn, cn, wqb, wkvb, qb, kvb, 0.125f * LOG2E);
    // attention
    attn_kernel<<<dim3(NSEQ / 128 * NB * NH), dim3(512), 0, stream>>>(qb, kvb, ao);
    // out = ao * Wo^T + x
    o_gemm<<<dim3(512), dim3(256), 0, stream>>>(ao, wob, out, x);
}

// Round 18
// 215.216 us; speedup vs baseline: 1.0111x; 1.0111x over previous
//
#include <hip/hip_runtime.h>
#include <hip/hip_bf16.h>
#include <stdint.h>

typedef __bf16 bf16;
typedef __bf16 bf16x8 __attribute__((ext_vector_type(8)));
typedef __bf16 bf16x4 __attribute__((ext_vector_type(4)));
typedef float f32x4 __attribute__((ext_vector_type(4)));
typedef unsigned u32x2 __attribute__((ext_vector_type(2)));

#define F_DIM 1024
#define NSEQ  2048
#define NB    4
#define NH    16
#define HD    64
#define MROWS (NB * NSEQ)  /* 8192 */
#define LOG2E 1.44269504088896340736f

__device__ __forceinline__ void gload_lds16(const void* g, void* l) {
    __builtin_amdgcn_global_load_lds(
        (__attribute__((address_space(1))) void*)g,
        (__attribute__((address_space(3))) void*)l,
        16, 0, 0);
}

__device__ __forceinline__ unsigned lds_addr(const void* p) {
    return (unsigned)(size_t)(__attribute__((address_space(3))) const void*)p;
}

__device__ __forceinline__ float exp2_fast(float x) {
    float r;
    asm("v_exp_f32 %0, %1" : "=v"(r) : "v"(x));
    return r;
}

__device__ __forceinline__ unsigned cvtpk_bf16(float lo, float hi) {
    unsigned r;
    asm("v_cvt_pk_bf16_f32 %0, %1, %2" : "=v"(r) : "v"(lo), "v"(hi));
    return r;
}

// ---------------------------------------------------------------------------
// Fused prep: blocks [0,8192) = double layernorm row; [8192,12288) = weight
// convert (dsts contiguous wqb|wkvb|wob). Both BW-bound; one launch.
// ---------------------------------------------------------------------------
__global__ __launch_bounds__(256) void prep_kernel(
    const float* __restrict__ x,
    const float* __restrict__ g1, const float* __restrict__ b1,
    const float* __restrict__ g2, const float* __restrict__ b2,
    bf16* __restrict__ xn, bf16* __restrict__ cn,
    const float* __restrict__ wq, const float* __restrict__ wkv,
    const float* __restrict__ wo, bf16* __restrict__ wdst)
{
    const int t = threadIdx.x;
    if (blockIdx.x >= MROWS) {
        const int i = (blockIdx.x - MROWS) * 256 + t;   // float4 units
        const float* src;
        int si;
        if (i < 262144)       { src = wq;  si = i; }
        else if (i < 786432)  { src = wkv; si = i - 262144; }
        else                  { src = wo;  si = i - 786432; }
        float4 v = reinterpret_cast<const float4*>(src)[si];
        bf16x4 o = { (bf16)v.x, (bf16)v.y, (bf16)v.z, (bf16)v.w };
        reinterpret_cast<bf16x4*>(wdst)[i] = o;
        return;
    }
    const int row = blockIdx.x;
    float4 v = reinterpret_cast<const float4*>(x + (size_t)row * F_DIM)[t];
    float s  = v.x + v.y + v.z + v.w;
    float ss = v.x * v.x + v.y * v.y + v.z * v.z + v.w * v.w;
#pragma unroll
    for (int m = 1; m < 64; m <<= 1) {
        s  += __shfl_xor(s, m);
        ss += __shfl_xor(ss, m);
    }
    __shared__ float red[8];
    const int w = t >> 6;
    if ((t & 63) == 0) { red[w] = s; red[4 + w] = ss; }
    __syncthreads();
    s  = red[0] + red[1] + red[2] + red[3];
    ss = red[4] + red[5] + red[6] + red[7];
    const float mu  = s * (1.0f / F_DIM);
    const float var = fmaxf(ss * (1.0f / F_DIM) - mu * mu, 0.0f);
    const float rs  = rsqrtf(var + 1e-5f);

    float4 G1 = reinterpret_cast<const float4*>(g1)[t];
    float4 B1 = reinterpret_cast<const float4*>(b1)[t];
    float4 G2 = reinterpret_cast<const float4*>(g2)[t];
    float4 B2 = reinterpret_cast<const float4*>(b2)[t];
    const float h0 = (v.x - mu) * rs, h1 = (v.y - mu) * rs;
    const float h2 = (v.z - mu) * rs, h3 = (v.w - mu) * rs;
    bf16x4 o1 = { (bf16)(h0 * G1.x + B1.x), (bf16)(h1 * G1.y + B1.y),
                  (bf16)(h2 * G1.z + B1.z), (bf16)(h3 * G1.w + B1.w) };
    bf16x4 o2 = { (bf16)(h0 * G2.x + B2.x), (bf16)(h1 * G2.y + B2.y),
                  (bf16)(h2 * G2.z + B2.z), (bf16)(h3 * G2.w + B2.w) };
    *reinterpret_cast<bf16x4*>(xn + (size_t)row * F_DIM + t * 4) = o1;
    *reinterpret_cast<bf16x4*>(cn + (size_t)row * F_DIM + t * 4) = o2;
}

// ---------------------------------------------------------------------------
// Merged Q/KV projection GEMM, K=1024, BK=32 (known-good). 1536 blocks:
//   flat < 512 : q  = xn * Wq^T  * qscale ; else kv = cn * Wkv^T. XCD-chunked.
// ---------------------------------------------------------------------------
__global__ __launch_bounds__(256, 2) void qkv_gemm(
    const bf16* __restrict__ xn, const bf16* __restrict__ cn,
    const bf16* __restrict__ wq, const bf16* __restrict__ wkv,
    bf16* __restrict__ qb, bf16* __restrict__ kvb, float qscale)
{
    __shared__ bf16 As[128 * 32];
    __shared__ bf16 Bs[128 * 32];
    const int t = threadIdx.x;
    const int lane = t & 63;
    const int w = t >> 6;
    const int wr = w >> 1, wc = w & 1;

    int flat = blockIdx.x;
    flat = (flat & 7) * 192 + (flat >> 3);          // XCD chunk (1536/8 = 192)

    const bf16 *A, *B;
    bf16* C;
    int N, bm, bn;
    float osc;
    if (flat < 512) {
        A = xn; B = wq; C = qb; N = 1024; osc = qscale;
        bm = (flat >> 3) * 128; bn = (flat & 7) * 128;
    } else {
        const int f = flat - 512;
        A = cn; B = wkv; C = kvb; N = 2048; osc = 1.0f;
        bm = (f >> 4) * 128; bn = (f & 15) * 128;
    }

    const int r = lane & 15;
    const int kg = (lane >> 4) * 8;

    f32x4 acc[4][4];
#pragma unroll
    for (int i = 0; i < 4; i++)
#pragma unroll
        for (int j = 0; j < 4; j++) acc[i][j] = (f32x4){0.f, 0.f, 0.f, 0.f};

    const int c0 = t, c1 = 256 + t;
    const size_t aoff0 = (size_t)(bm + (c0 >> 2)) * F_DIM + (c0 & 3) * 8;
    const size_t aoff1 = (size_t)(bm + (c1 >> 2)) * F_DIM + (c1 & 3) * 8;
    const size_t boff0 = (size_t)(bn + (c0 >> 2)) * F_DIM + (c0 & 3) * 8;
    const size_t boff1 = (size_t)(bn + (c1 >> 2)) * F_DIM + (c1 & 3) * 8;
    bf16* lA0 = As + (size_t)(0 * 256 + w * 64) * 8;
    bf16* lA1 = As + (size_t)(1 * 256 + w * 64) * 8;
    bf16* lB0 = Bs + (size_t)(0 * 256 + w * 64) * 8;
    bf16* lB1 = Bs + (size_t)(1 * 256 + w * 64) * 8;

    for (int kt = 0; kt < F_DIM; kt += 32) {
        gload_lds16(A + aoff0 + kt, lA0);
        gload_lds16(A + aoff1 + kt, lA1);
        gload_lds16(B + boff0 + kt, lB0);
        gload_lds16(B + boff1 + kt, lB1);
        __syncthreads();
        bf16x8 af[4], bfr[4];
#pragma unroll
        for (int mi = 0; mi < 4; mi++)
            af[mi] = *(const bf16x8*)(As + (wr * 64 + mi * 16 + r) * 32 + kg);
#pragma unroll
        for (int ni = 0; ni < 4; ni++)
            bfr[ni] = *(const bf16x8*)(Bs + (wc * 64 + ni * 16 + r) * 32 + kg);
#pragma unroll
        for (int mi = 0; mi < 4; mi++)
#pragma unroll
            for (int ni = 0; ni < 4; ni++)
                acc[mi][ni] = __builtin_amdgcn_mfma_f32_16x16x32_bf16(
                    af[mi], bfr[ni], acc[mi][ni], 0, 0, 0);
        __syncthreads();
    }

    const int g = lane >> 4;
#pragma unroll
    for (int mi = 0; mi < 4; mi++) {
#pragma unroll
        for (int ni = 0; ni < 4; ni++) {
            const int col = bn + wc * 64 + ni * 16 + r;
#pragma unroll
            for (int j = 0; j < 4; j++) {
                const int row = bm + wr * 64 + mi * 16 + g * 4 + j;
                C[(size_t)row * N + col] = (bf16)(acc[mi][ni][j] * osc);
            }
        }
    }
}

// ---------------------------------------------------------------------------
// Output GEMM: out = ao * Wo^T + x (fp32). BK=32. 512 blocks, XCD-chunked.
// ---------------------------------------------------------------------------
__global__ __launch_bounds__(256, 2) void o_gemm(
    const bf16* __restrict__ A, const bf16* __restrict__ B,
    float* __restrict__ Cf, const float* __restrict__ skip)
{
    __shared__ bf16 As[128 * 32];
    __shared__ bf16 Bs[128 * 32];
    const int t = threadIdx.x;
    const int lane = t & 63;
    const int w = t >> 6;
    const int wr = w >> 1, wc = w & 1;

    int flat = blockIdx.x;                          // 512 blocks: 64 M x 8 N
    flat = (flat & 7) * 64 + (flat >> 3);           // XCD chunk
    const int bm = (flat >> 3) * 128;
    const int bn = (flat & 7) * 128;

    const int r = lane & 15;
    const int kg = (lane >> 4) * 8;

    f32x4 acc[4][4];
#pragma unroll
    for (int i = 0; i < 4; i++)
#pragma unroll
        for (int j = 0; j < 4; j++) acc[i][j] = (f32x4){0.f, 0.f, 0.f, 0.f};

    const int c0 = t, c1 = 256 + t;
    const size_t aoff0 = (size_t)(bm + (c0 >> 2)) * F_DIM + (c0 & 3) * 8;
    const size_t aoff1 = (size_t)(bm + (c1 >> 2)) * F_DIM + (c1 & 3) * 8;
    const size_t boff0 = (size_t)(bn + (c0 >> 2)) * F_DIM + (c0 & 3) * 8;
    const size_t boff1 = (size_t)(bn + (c1 >> 2)) * F_DIM + (c1 & 3) * 8;
    bf16* lA0 = As + (size_t)(0 * 256 + w * 64) * 8;
    bf16* lA1 = As + (size_t)(1 * 256 + w * 64) * 8;
    bf16* lB0 = Bs + (size_t)(0 * 256 + w * 64) * 8;
    bf16* lB1 = Bs + (size_t)(1 * 256 + w * 64) * 8;

    for (int kt = 0; kt < F_DIM; kt += 32) {
        gload_lds16(A + aoff0 + kt, lA0);
        gload_lds16(A + aoff1 + kt, lA1);
        gload_lds16(B + boff0 + kt, lB0);
        gload_lds16(B + boff1 + kt, lB1);
        __syncthreads();
        bf16x8 af[4], bfr[4];
#pragma unroll
        for (int mi = 0; mi < 4; mi++)
            af[mi] = *(const bf16x8*)(As + (wr * 64 + mi * 16 + r) * 32 + kg);
#pragma unroll
        for (int ni = 0; ni < 4; ni++)
            bfr[ni] = *(const bf16x8*)(Bs + (wc * 64 + ni * 16 + r) * 32 + kg);
#pragma unroll
        for (int mi = 0; mi < 4; mi++)
#pragma unroll
            for (int ni = 0; ni < 4; ni++)
                acc[mi][ni] = __builtin_amdgcn_mfma_f32_16x16x32_bf16(
                    af[mi], bfr[ni], acc[mi][ni], 0, 0, 0);
        __syncthreads();
    }

    const int g = lane >> 4;
#pragma unroll
    for (int mi = 0; mi < 4; mi++) {
#pragma unroll
        for (int ni = 0; ni < 4; ni++) {
            const int col = bn + wc * 64 + ni * 16 + r;
#pragma unroll
            for (int j = 0; j < 4; j++) {
                const int row = bm + wr * 64 + mi * 16 + g * 4 + j;
                Cf[(size_t)row * F_DIM + col] =
                    acc[mi][ni][j] + skip[(size_t)row * F_DIM + col];
            }
        }
    }
}

// ---------------------------------------------------------------------------
// Flash attention — converged configuration (best measured: 123.4 us, x4
// reproductions). Single-buffer KVBLK=128 (v17 A/B proved the staging drain
// is TLP-hidden; dbuf/reg-stage/split-restage all regressed). 8 waves,
// QBLK=128, LDS 51.2KB, waves_per_eu(4,5), early P-pack, exp2 softmax +
// defer-max, XOR-swz K, subtiled V + ds_read_b64_tr_b16, setprio, XCD chunk.
// ---------------------------------------------------------------------------
__global__ __launch_bounds__(512)
__attribute__((amdgpu_waves_per_eu(4, 5)))
void attn_kernel(
    const bf16* __restrict__ q, const bf16* __restrict__ kvp,
    bf16* __restrict__ o)
{
    __shared__ __align__(16) bf16 Ks[128 * 64];     // [kv][64d], 16B-chunk XOR-swz
    __shared__ __align__(16) bf16 Vs[128 * 64];     // [kvb=32][dblk=4][4kv][16d]
    __shared__ __align__(16) bf16 Ps[8][16 * 72];   // per-wave P half-tile [q][64kv]

    const int bid = blockIdx.x;
    const int idx = (bid & 7) * 128 + (bid >> 3);   // XCD-chunked (1024 % 8 == 0)
    const int bh = idx >> 4;
    const int qt = idx & 15;
    const int b = bh >> 4, h = bh & 15;

    const int t = threadIdx.x, lane = t & 63, w = t >> 6;
    const int r = lane & 15, g = lane >> 4;

    const size_t rowq = (size_t)b * NSEQ;

    // --- staging source offsets; dest 16B chunk p = c*512 + t, c=0..1 ---
    size_t ksrc[2], vsrc[2];
#pragma unroll
    for (int c = 0; c < 2; c++) {
        const int p = c * 512 + t;
        const int krow = p >> 3;                    // 0..127
        const int kcol = (p & 7) ^ (krow & 7);
        ksrc[c] = (size_t)(rowq + krow) * (2 * F_DIM) + h * HD + kcol * 8;
        const int kvb = p >> 5, dblk = (p >> 3) & 3;
        const int kvl = (p & 7) >> 1, d8 = p & 1;
        vsrc[c] = (size_t)(rowq + kvb * 4 + kvl) * (2 * F_DIM) + F_DIM + h * HD
                  + dblk * 16 + d8 * 8;
    }

    // --- Q fragments (B-operand: lane holds Q[q=r][d = kk*32 + g*8 ..]) ---
    const int q0 = qt * 128 + w * 16;
    bf16x8 qf[2];
#pragma unroll
    for (int kk = 0; kk < 2; kk++)
        qf[kk] = *(const bf16x8*)(q + (rowq + q0 + r) * F_DIM + h * HD + kk * 32 + g * 8);

    f32x4 oacc[4];
#pragma unroll
    for (int i = 0; i < 4; i++) oacc[i] = (f32x4){0.f, 0.f, 0.f, 0.f};
    float m_r = -1e30f, l_r = 0.f;

    const unsigned va    = lds_addr(Vs) + (unsigned)(g * 1024 + r * 8);
    const unsigned pbase = lds_addr(&Ps[w][0]) + (unsigned)((r * 72 + g * 8) * 2);

    for (int kv0 = 0; kv0 < NSEQ; kv0 += 128) {
        // barrier-1: all waves done reading previous tile's LDS
        asm volatile("s_barrier" ::: "memory");
        const size_t koff = (size_t)kv0 * (2 * F_DIM);
#pragma unroll
        for (int c = 0; c < 2; c++) {
            gload_lds16(kvp + ksrc[c] + koff, Ks + (size_t)(c * 512 + (t & ~63)) * 8);
            gload_lds16(kvp + vsrc[c] + koff, Vs + (size_t)(c * 512 + (t & ~63)) * 8);
        }
        // barrier-2: drain loads, all data in LDS
        asm volatile("s_waitcnt vmcnt(0)\n\ts_barrier" ::: "memory");

        // --- S^T = K * Q^T : lane holds S[kv = nt*16 + g*4 + j][q = r] ---
        f32x4 s4[8];
#pragma unroll
        for (int nt = 0; nt < 8; nt++) s4[nt] = (f32x4){0.f, 0.f, 0.f, 0.f};
        __builtin_amdgcn_s_setprio(1);
#pragma unroll
        for (int kk = 0; kk < 2; kk++) {
#pragma unroll
            for (int nt = 0; nt < 8; nt++) {
                const unsigned lb = (unsigned)((nt * 16 + r) * 128 + kk * 64 + g * 16)
                                    ^ (unsigned)((r & 7) << 4);
                bf16x8 kf = *(const bf16x8*)((const char*)Ks + lb);
                s4[nt] = __builtin_amdgcn_mfma_f32_16x16x32_bf16(kf, qf[kk], s4[nt], 0, 0, 0);
            }
        }
        __builtin_amdgcn_s_setprio(0);

        // --- online softmax in exp2 domain, lane-parallel (q = r) ---
        float mx = s4[0][0];
#pragma unroll
        for (int nt = 0; nt < 8; nt++)
#pragma unroll
            for (int j = 0; j < 4; j++) mx = fmaxf(mx, s4[nt][j]);
        mx = fmaxf(mx, __shfl_xor(mx, 16));
        mx = fmaxf(mx, __shfl_xor(mx, 32));
        if (!__all(mx <= m_r + 8.0f)) {             // defer-max (T13)
            const float mnew = fmaxf(m_r, mx);
            const float alpha = exp2_fast(m_r - mnew);
            l_r *= alpha;
#pragma unroll
            for (int j = 0; j < 4; j++) {
                const float aj = __shfl(alpha, g * 4 + j);
#pragma unroll
                for (int ntd = 0; ntd < 4; ntd++) oacc[ntd][j] *= aj;
            }
            m_r = mnew;
        }
        // exp + sum + immediate bf16 pack (frees s4 before PV)
        u32x2 pa2[8];
        float ps = 0.f;
#pragma unroll
        for (int nt = 0; nt < 8; nt++) {
            const float e0 = exp2_fast(s4[nt][0] - m_r);
            const float e1 = exp2_fast(s4[nt][1] - m_r);
            const float e2 = exp2_fast(s4[nt][2] - m_r);
            const float e3 = exp2_fast(s4[nt][3] - m_r);
            ps += (e0 + e1) + (e2 + e3);
            pa2[nt] = (u32x2){ cvtpk_bf16(e0, e1), cvtpk_bf16(e2, e3) };
        }
        ps += __shfl_xor(ps, 16);
        ps += __shfl_xor(ps, 32);
        l_r += ps;

        // --- PV in two 64-kv halves, reusing the per-wave P buffer ---
#pragma unroll
        for (int hh = 0; hh < 2; hh++) {
#pragma unroll
            for (int nt2 = 0; nt2 < 4; nt2++)
                *(u32x2*)&Ps[w][r * 72 + nt2 * 16 + g * 4] = pa2[hh * 4 + nt2];
            asm volatile("s_waitcnt lgkmcnt(0)" ::: "memory");  // writes landed

            bf16x8 pf[2];
            u32x2 vt[2][4][2];
#pragma unroll
            for (int kk2 = 0; kk2 < 2; kk2++) {
                const unsigned pa = pbase + (unsigned)(kk2 * 64);
                asm volatile("ds_read_b128 %0, %1" : "=v"(pf[kk2]) : "v"(pa));
                const int kkg = hh * 2 + kk2;
#pragma unroll
                for (int ntd = 0; ntd < 4; ntd++) {
                    const unsigned a = va + (unsigned)(kkg * 4096 + ntd * 128);
                    asm volatile("ds_read_b64_tr_b16 %0, %2\n\t"
                                 "ds_read_b64_tr_b16 %1, %2 offset:512"
                                 : "=&v"(vt[kk2][ntd][0]), "=&v"(vt[kk2][ntd][1])
                                 : "v"(a));
                }
            }
            asm volatile("s_waitcnt lgkmcnt(0)" ::: "memory");
            __builtin_amdgcn_sched_barrier(0);

            __builtin_amdgcn_s_setprio(1);
#pragma unroll
            for (int kk2 = 0; kk2 < 2; kk2++)
#pragma unroll
                for (int ntd = 0; ntd < 4; ntd++) {
                    union { u32x2 hl[2]; bf16x8 v; } u;
                    u.hl[0] = vt[kk2][ntd][0];
                    u.hl[1] = vt[kk2][ntd][1];
                    oacc[ntd] = __builtin_amdgcn_mfma_f32_16x16x32_bf16(pf[kk2], u.v, oacc[ntd], 0, 0, 0);
                }
            __builtin_amdgcn_s_setprio(0);
        }
    }

    // --- epilogue: normalize + store ---
    float rl[4];
#pragma unroll
    for (int j = 0; j < 4; j++) {
        const float lj = __shfl(l_r, g * 4 + j);
        rl[j] = 1.0f / lj;
    }
#pragma unroll
    for (int ntd = 0; ntd < 4; ntd++)
#pragma unroll
        for (int j = 0; j < 4; j++) {
            const int row = q0 + g * 4 + j;
            o[(rowq + row) * F_DIM + h * HD + ntd * 16 + r] =
                (bf16)(oacc[ntd][j] * rl[j]);
        }
}

// ---------------------------------------------------------------------------
extern "C" void kernel_launch(void* const* d_in, const int* in_sizes, int n_in,
                              void* d_out, int out_size, void* d_ws, size_t ws_size,
                              hipStream_t stream)
{
    const float* x     = (const float*)d_in[0];
    const float* Wq    = (const float*)d_in[1];
    const float* Wkv   = (const float*)d_in[2];
    const float* Wo    = (const float*)d_in[3];
    const float* ln_g  = (const float*)d_in[4];
    const float* ln_b  = (const float*)d_in[5];
    const float* lnc_g = (const float*)d_in[6];
    const float* lnc_b = (const float*)d_in[7];
    float* out = (float*)d_out;

    bf16* xn   = (bf16*)d_ws;
    bf16* cn   = xn  + (size_t)MROWS * F_DIM;
    bf16* qb   = cn  + (size_t)MROWS * F_DIM;
    bf16* kvb  = qb  + (size_t)MROWS * F_DIM;
    bf16* wqb  = kvb + (size_t)MROWS * 2 * F_DIM;   // wqb|wkvb|wob contiguous
    bf16* wkvb = wqb + (size_t)F_DIM * F_DIM;
    bf16* wob  = wkvb + (size_t)2 * F_DIM * F_DIM;
    bf16* ao   = xn;  // xn dead after qkv-GEMM

    // layernorms + weight converts fused into one launch
    prep_kernel<<<dim3(MROWS + 4096), dim3(256), 0, stream>>>(
        x, ln_g, ln_b, lnc_g, lnc_b, xn, cn, Wq, Wkv, Wo, wqb);

    // q = (xn * Wq^T) * 0.125 * log2(e) ; kv = cn * Wkv^T   (one launch)
    qkv_gemm<<<dim3(1536), dim3(256), 0, stream>>>(
        xn, cn, wqb, wkvb, qb, kvb, 0.125f * LOG2E);
    // attention
    attn_kernel<<<dim3(NSEQ / 128 * NB * NH), dim3(512), 0, stream>>>(qb, kvb, ao);
    // out = ao * Wo^T + x
    o_gemm<<<dim3(512), dim3(256), 0, stream>>>(ao, wob, out, x);
}